// Round 18
// baseline (50.007 us; speedup 1.0000x reference)
//
#include <hip/hip_runtime.h>
#include <hip/hip_bf16.h>

typedef __attribute__((ext_vector_type(4))) int i32x4;

#define NROW 8192
#define DIM 512          // elements per row; i8 row = 512 bytes
#define BHALF 4096
#define NB 64            // number of 128-row blocks
#define BM 128
#define NPAIR 2080       // NB*(NB+1)/2
#define XCHUNK 260       // 2080/8

__device__ __forceinline__ void gload_lds16(const void* g, void* l) {
  __builtin_amdgcn_global_load_lds(
      (const __attribute__((address_space(1))) void*)g,
      (__attribute__((address_space(3))) void*)l,
      16, 0, 0);
}

// DPP 16-lane sum (row_ror 8/4/2/1): VALU pipe, no LDS traffic.
template <int CTRL>
__device__ __forceinline__ float dpp_ror_add(float v) {
  const int r = __builtin_amdgcn_update_dpp(0, __float_as_int(v), CTRL, 0xf, 0xf, false);
  return v + __int_as_float(r);
}
__device__ __forceinline__ float sum16_dpp(float v) {
  v = dpp_ror_add<0x128>(v);   // row_ror:8
  v = dpp_ror_add<0x124>(v);   // row_ror:4
  v = dpp_ror_add<0x122>(v);   // row_ror:2
  v = dpp_ror_add<0x121>(v);   // row_ror:1
  return v;
}

// ---------------- Kernel 1: row L2-normalize fp32 -> int8 (wave per row) ----------------
__global__ __launch_bounds__(256) void normalize_kernel(const float* __restrict__ in,
                                                        signed char* __restrict__ out) {
  const int w = threadIdx.x >> 6, lane = threadIdx.x & 63;
  const int row = blockIdx.x * 4 + w;
  const float4* src = (const float4*)(in + (size_t)row * DIM) + lane * 2;
  const float4 v0 = src[0], v1 = src[1];
  float ss = v0.x * v0.x + v0.y * v0.y + v0.z * v0.z + v0.w * v0.w
           + v1.x * v1.x + v1.y * v1.y + v1.z * v1.z + v1.w * v1.w;
  #pragma unroll
  for (int m = 1; m < 64; m <<= 1) ss += __shfl_xor(ss, m);
  const float s127 = 127.0f / fmaxf(sqrtf(ss), 1e-12f);
  float vv[8] = {v0.x, v0.y, v0.z, v0.w, v1.x, v1.y, v1.z, v1.w};
  signed char q[8];
  #pragma unroll
  for (int j = 0; j < 8; ++j) {
    int qi = __float2int_rn(vv[j] * s127);
    qi = qi > 127 ? 127 : (qi < -127 ? -127 : qi);
    q[j] = (signed char)qi;
  }
  *(int2*)(out + (size_t)row * 512 + lane * 8) = *(const int2*)q;
}

// ---------------- Kernel 2: symmetric 128x128 pair-tile Gram (int8, BARRIER-FREE) ----------------
// 2080 blocks (ib<=jb pairs), 256 threads = 4 waves (2x2), 4x4 frags of 16x16x64.
// Each wave stages its OWN copy of A-half wy and B-half wx into a PRIVATE
// 16 KB LDS region (2-deep ring of 8 KB: A 4KB @0, B 4KB @4096), synchronized
// only by its own counted vmcnt -- ZERO barriers in the K-loop. Waves drift
// freely; 8 independent pipelines/CU (2 blocks x 4 waves). Staging duplicates
// each half 2x (L2-served). WAR safe per-wave: buf reads of iter t-1 complete
// before that iter's MFMAs (compiler lgkm waits); STAGE(t+1) issues after.
// Swizzle identical to r17 (measured 0 conflicts).
__global__ __launch_bounds__(256, 2) void pair_gram_kernel(const signed char* __restrict__ f8,
                                                           float* __restrict__ psum,
                                                           float* __restrict__ posArr) {
  __shared__ __align__(16) char lds[65536];   // 4 waves x 16 KB private

  // --- XCD swizzle + 16x16 macro-tiled triangular pair decode (scalar-uniform) ---
  const int bid = blockIdx.x;
  const int wg = (bid & 7) * XCHUNK + (bid >> 3);
  int rem = wg, MI = 0, MJ = 0;
  {
    bool brk = false;
    for (MI = 0; MI < 4 && !brk; ++MI) {
      for (MJ = MI; MJ < 4; ++MJ) {
        const int sz = (MI == MJ) ? 136 : 256;
        if (rem < sz) { brk = true; break; }
        rem -= sz;
      }
    }
    if (brk) --MI;
  }
  int ib, jb;
  if (MI == MJ) {          // 16x16 triangle: 136 entries
    int i = 0, b = 0;
    while (b + (16 - i) <= rem) { b += 16 - i; ++i; }
    ib = MI * 16 + i; jb = MI * 16 + i + (rem - b);
  } else {
    ib = MI * 16 + (rem >> 4); jb = MJ * 16 + (rem & 15);
  }
  const bool has_pos = (jb == ib + 32);
  const bool isdiag = (ib == jb);

  const int tid = threadIdx.x;
  const int lane = tid & 63;
  const int w = tid >> 6;            // wave 0..3
  const int wy = w >> 1;             // row half (0/1)
  const int wx = w & 1;              // col half (0/1)
  const int fr = lane & 15;          // fragment row/col index
  const int g = lane >> 4;           // k-group

  // private staging: this wave stages A rows [ib*128+wy*64, +64) and
  // B rows [jb*128+wx*64, +64). 4 gloads each (16 rows per gload).
  // lane l: row (l>>2) within group, chunk (l&3)^(((l>>2)&15)>>1 &3) inverse-swz.
  const int srow4 = lane >> 2;                       // row 0..15 in group
  const int schunk = (lane & 3) ^ ((lane >> 3) & 3); // = (l&3) ^ ((srow4>>1)&3)
  const signed char* gA = f8 + (size_t)(ib * BM + wy * 64 + srow4) * 512 + schunk * 16;
  const signed char* gB = f8 + (size_t)(jb * BM + wx * 64 + srow4) * 512 + schunk * 16;
  char* const myLds = lds + w * 16384;   // private: buf[2] x { A 4KB @0, B 4KB @4096 }

  i32x4 acc[4][4];
  const i32x4 izero = {0, 0, 0, 0};
  #pragma unroll
  for (int mi = 0; mi < 4; ++mi)
    #pragma unroll
    for (int ni = 0; ni < 4; ++ni) acc[mi][ni] = izero;

  // fragment reads (private region): row r at byte r*64, k-chunk (g^((fr>>1)&3))*16
  const int sk = (g ^ ((fr >> 1) & 3)) * 16;
  const int arow = fr * 64 + sk;          // + mi*1024
  const int brow = 4096 + fr * 64 + sk;   // + ni*1024

  #define STAGE(buf, kt)                                                        \
    {                                                                           \
      char* _d = myLds + (buf) * 8192;                                          \
      const int _kn = (kt) * 64;                                                \
      _Pragma("unroll")                                                         \
      for (int q = 0; q < 4; ++q) {                                             \
        gload_lds16(gA + _kn + (size_t)(q * 16) * 512, _d + q * 1024);          \
        gload_lds16(gB + _kn + (size_t)(q * 16) * 512, _d + 4096 + q * 1024);   \
      }                                                                         \
    }

  STAGE(0, 0);   // prologue: tile 0 in flight (8 gloads/wave)

  #pragma unroll
  for (int t = 0; t < 8; ++t) {
    if (t < 7) {
      STAGE((t + 1) & 1, t + 1);   // 16 outstanding; covered by compute(t)
      asm volatile("s_waitcnt vmcnt(8)" ::: "memory");   // stage(t) landed
    } else {
      asm volatile("s_waitcnt vmcnt(0)" ::: "memory");   // tail
    }

    const char* base = myLds + (t & 1) * 8192;
    i32x4 aF[4], bF[4];
    #pragma unroll
    for (int mi = 0; mi < 4; ++mi) aF[mi] = *(const i32x4*)(base + arow + mi * 1024);
    #pragma unroll
    for (int ni = 0; ni < 4; ++ni) bF[ni] = *(const i32x4*)(base + brow + ni * 1024);
    __builtin_amdgcn_s_setprio(1);
    #pragma unroll
    for (int mi = 0; mi < 4; ++mi)
      #pragma unroll
      for (int ni = 0; ni < 4; ++ni)
        acc[mi][ni] = __builtin_amdgcn_mfma_i32_16x16x64_i8(aF[mi], bF[ni], acc[mi][ni], 0, 0, 0);
    __builtin_amdgcn_s_setprio(0);
  }
  #undef STAGE

  // ---- epilogue: exp, row-sums + col-sums; pos-pair direct write ----
  const float SC10 = 10.0f / 16129.0f;
  float rsum[4][4], csum[4];
  #pragma unroll
  for (int mi = 0; mi < 4; ++mi)
    #pragma unroll
    for (int r = 0; r < 4; ++r) rsum[mi][r] = 0.f;
  #pragma unroll
  for (int ni = 0; ni < 4; ++ni) csum[ni] = 0.f;

  #pragma unroll
  for (int mi = 0; mi < 4; ++mi) {
    #pragma unroll
    for (int ni = 0; ni < 4; ++ni) {
      const int lc = wx * 64 + ni * 16 + fr;
      #pragma unroll
      for (int r = 0; r < 4; ++r) {
        const int lr = wy * 64 + mi * 16 + g * 4 + r;
        const float l10 = (float)acc[mi][ni][r] * SC10;
        const float e = (isdiag && lc == lr) ? 0.f : __expf(l10 - 10.0f);
        rsum[mi][r] += e;
        csum[ni] += e;
        if (has_pos && lc == lr) {
          const float d = (float)acc[mi][ni][r] * (1.0f / 16129.0f);
          posArr[ib * BM + lr] = d;
          posArr[jb * BM + lr] = d;
        }
      }
    }
  }

  // row side: 16-lane DPP reduce (VALU); col side: 2 shuffles over g bits
  #pragma unroll
  for (int mi = 0; mi < 4; ++mi)
    #pragma unroll
    for (int r = 0; r < 4; ++r) rsum[mi][r] = sum16_dpp(rsum[mi][r]);
  #pragma unroll
  for (int ni = 0; ni < 4; ++ni) {
    float a = csum[ni];
    a += __shfl_xor(a, 16);
    a += __shfl_xor(a, 32);
    csum[ni] = a;
  }

  // cross-wave combine via LDS (aliases tile buffers; safe after barrier)
  __syncthreads();
  float* sc = (float*)lds;  // rS[wx][128]@0, cS[wy][128]@256 (floats)
  if (fr == 0) {
    #pragma unroll
    for (int mi = 0; mi < 4; ++mi)
      #pragma unroll
      for (int r = 0; r < 4; ++r) {
        const int row = wy * 64 + mi * 16 + g * 4 + r;
        sc[wx * 128 + row] = rsum[mi][r];
      }
  }
  if (g == 0) {
    #pragma unroll
    for (int ni = 0; ni < 4; ++ni) {
      const int col = wx * 64 + ni * 16 + fr;
      sc[256 + wy * 128 + col] = csum[ni];
    }
  }
  __syncthreads();

  if (tid < 128) {                     // rows of block ib -> slot jb
    const int row = tid;
    psum[(size_t)jb * NROW + ib * BM + row] = sc[row] + sc[128 + row];
  } else if (!isdiag) {                // rows of block jb -> slot ib (transpose side)
    const int col = tid - 128;
    psum[(size_t)ib * NROW + jb * BM + col] = sc[256 + col] + sc[384 + col];
  }
}

// ---------------- Kernel 3a: per-row loss, 256 partials (wide-parallel gather) ----------------
__global__ __launch_bounds__(128) void loss_stage1(const float* __restrict__ psum,
                                                   const float* __restrict__ posArr,
                                                   float* __restrict__ partial) {
  const int r5 = threadIdx.x & 31;       // row within block
  const int grp = threadIdx.x >> 5;      // slot group 0..3 (16 slots each)
  const int row = blockIdx.x * 32 + r5;
  float s = 0.f;
  #pragma unroll 4
  for (int sl = grp * 16; sl < grp * 16 + 16; ++sl)
    s += psum[(size_t)sl * NROW + row];
  __shared__ float red[4][32];
  red[grp][r5] = s;
  __syncthreads();
  if (threadIdx.x < 32) {
    const float tot = red[0][r5] + red[1][r5] + red[2][r5] + red[3][r5];
    float local = logf(tot) + 10.0f - 10.0f * posArr[row];
    #pragma unroll
    for (int m = 1; m < 32; m <<= 1) local += __shfl_xor(local, m);
    if (r5 == 0) partial[blockIdx.x] = local;
  }
}

// ---------------- Kernel 3b: final scalar (256 partials) ----------------
__global__ __launch_bounds__(256) void loss_stage2(const float* __restrict__ partial,
                                                   float* __restrict__ out) {
  float v = partial[threadIdx.x];
  #pragma unroll
  for (int m = 1; m < 64; m <<= 1) v += __shfl_xor(v, m);
  __shared__ float red[4];
  if ((threadIdx.x & 63) == 0) red[threadIdx.x >> 6] = v;
  __syncthreads();
  if (threadIdx.x == 0)
    out[0] = (red[0] + red[1] + red[2] + red[3]) * (1.0f / (float)BHALF);
}

extern "C" void kernel_launch(void* const* d_in, const int* in_sizes, int n_in,
                              void* d_out, int out_size, void* d_ws, size_t ws_size,
                              hipStream_t stream) {
  const float* feat = (const float*)d_in[0];
  char* ws = (char*)d_ws;
  signed char* f8 = (signed char*)ws;                              // 4 MB
  float* psum = (float*)(ws + (size_t)NROW * 512);                 // NB*NROW floats (2 MB)
  float* posArr = psum + (size_t)NB * NROW;                        // 32 KB
  float* partial = posArr + NROW;                                  // 1 KB
  float* out = (float*)d_out;

  normalize_kernel<<<NROW / 4, 256, 0, stream>>>(feat, f8);
  pair_gram_kernel<<<NPAIR, 256, 0, stream>>>(f8, psum, posArr);
  loss_stage1<<<NROW / 32, 128, 0, stream>>>(psum, posArr, partial);
  loss_stage2<<<1, 256, 0, stream>>>(partial, out);
}

// Round 19
// 42.027 us; speedup vs baseline: 1.1899x; 1.1899x over previous
//
#include <hip/hip_runtime.h>
#include <hip/hip_bf16.h>

typedef __attribute__((ext_vector_type(4))) int i32x4;

#define NROW 8192
#define DIM 512          // elements per row; i8 row = 512 bytes
#define BHALF 4096
#define NB 64            // number of 128-row blocks
#define BM 128
#define NPAIR 2080       // NB*(NB+1)/2
#define XCHUNK 260       // 2080/8

__device__ __forceinline__ void gload_lds16(const void* g, void* l) {
  __builtin_amdgcn_global_load_lds(
      (const __attribute__((address_space(1))) void*)g,
      (__attribute__((address_space(3))) void*)l,
      16, 0, 0);
}

// DPP 16-lane sum (row_ror 8/4/2/1): VALU pipe, no LDS traffic.
template <int CTRL>
__device__ __forceinline__ float dpp_ror_add(float v) {
  const int r = __builtin_amdgcn_update_dpp(0, __float_as_int(v), CTRL, 0xf, 0xf, false);
  return v + __int_as_float(r);
}
__device__ __forceinline__ float sum16_dpp(float v) {
  v = dpp_ror_add<0x128>(v);   // row_ror:8
  v = dpp_ror_add<0x124>(v);   // row_ror:4
  v = dpp_ror_add<0x122>(v);   // row_ror:2
  v = dpp_ror_add<0x121>(v);   // row_ror:1
  return v;
}

// ---------------- Kernel 1: row L2-normalize fp32 -> int8 (wave per row) ----------------
__global__ __launch_bounds__(256) void normalize_kernel(const float* __restrict__ in,
                                                        signed char* __restrict__ out) {
  const int w = threadIdx.x >> 6, lane = threadIdx.x & 63;
  const int row = blockIdx.x * 4 + w;
  const float4* src = (const float4*)(in + (size_t)row * DIM) + lane * 2;
  const float4 v0 = src[0], v1 = src[1];
  float ss = v0.x * v0.x + v0.y * v0.y + v0.z * v0.z + v0.w * v0.w
           + v1.x * v1.x + v1.y * v1.y + v1.z * v1.z + v1.w * v1.w;
  #pragma unroll
  for (int m = 1; m < 64; m <<= 1) ss += __shfl_xor(ss, m);
  const float s127 = 127.0f / fmaxf(sqrtf(ss), 1e-12f);
  float vv[8] = {v0.x, v0.y, v0.z, v0.w, v1.x, v1.y, v1.z, v1.w};
  signed char q[8];
  #pragma unroll
  for (int j = 0; j < 8; ++j) {
    int qi = __float2int_rn(vv[j] * s127);
    qi = qi > 127 ? 127 : (qi < -127 ? -127 : qi);
    q[j] = (signed char)qi;
  }
  *(int2*)(out + (size_t)row * 512 + lane * 8) = *(const int2*)q;
}

// ---------------- Kernel 2: symmetric 128x128 pair-tile Gram (int8, 3-buf counted ring) ----------------
// r17 structure (best measured: 42.3 total) with ONE change: s_setprio REMOVED.
// T5 is documented negative on non-phase-split GEMM (m190); here every wave
// raising prio during its MFMA burst deprioritizes SIMD-mates' ds_read/gload
// issue -> mutual DS-pipe starvation across the 3 co-resident blocks.
// 2080 blocks (ib<=jb pairs), 256 threads = 4 waves (2x2), 4x4 frags of
// 16x16x64 i8. K-tile 64 B (8 tiles), 3 buffers (48 KB -> 3 blocks/CU).
// Per iter: raw s_barrier -> STAGE(t+2) -> counted vmcnt(8) -> compute(t).
__global__ __launch_bounds__(256, 4) void pair_gram_kernel(const signed char* __restrict__ f8,
                                                           float* __restrict__ psum,
                                                           float* __restrict__ posArr) {
  __shared__ __align__(16) char lds[49152];   // buf[3]: A[128][64B] @+0, B @+8192

  // --- XCD swizzle + 16x16 macro-tiled triangular pair decode (scalar-uniform) ---
  const int bid = blockIdx.x;
  const int wg = (bid & 7) * XCHUNK + (bid >> 3);
  int rem = wg, MI = 0, MJ = 0;
  {
    bool brk = false;
    for (MI = 0; MI < 4 && !brk; ++MI) {
      for (MJ = MI; MJ < 4; ++MJ) {
        const int sz = (MI == MJ) ? 136 : 256;
        if (rem < sz) { brk = true; break; }
        rem -= sz;
      }
    }
    if (brk) --MI;
  }
  int ib, jb;
  if (MI == MJ) {          // 16x16 triangle: 136 entries
    int i = 0, b = 0;
    while (b + (16 - i) <= rem) { b += 16 - i; ++i; }
    ib = MI * 16 + i; jb = MI * 16 + i + (rem - b);
  } else {
    ib = MI * 16 + (rem >> 4); jb = MJ * 16 + (rem & 15);
  }
  const bool has_pos = (jb == ib + 32);
  const bool isdiag = (ib == jb);

  const int tid = threadIdx.x;
  const int lane = tid & 63;
  const int w = tid >> 6;            // wave 0..3
  const int wy = w >> 1;             // row half (0/1)
  const int wx = w & 1;              // col half (0/1)
  const int fr = lane & 15;          // fragment row/col index
  const int g = lane >> 4;           // k-group

  // staging: wave w covers rows w*32..+32 (2 gloads of 16 rows); lane l:
  // row +l>>2, lds-chunk l&3, global chunk (l&3)^((l>>3)&3) (inverse swizzle).
  const int srow4 = lane >> 2;
  const int schunk = (lane & 3) ^ ((lane >> 3) & 3);
  const signed char* gA = f8 + (size_t)(ib * BM + w * 32 + srow4) * 512 + schunk * 16;
  const signed char* gB = f8 + (size_t)(jb * BM + w * 32 + srow4) * 512 + schunk * 16;

  i32x4 acc[4][4];
  const i32x4 izero = {0, 0, 0, 0};
  #pragma unroll
  for (int mi = 0; mi < 4; ++mi)
    #pragma unroll
    for (int ni = 0; ni < 4; ++ni) acc[mi][ni] = izero;

  // fragment reads: row r at byte r*64, k-chunk (g ^ ((fr>>1)&3))*16
  const int sk = (g ^ ((fr >> 1) & 3)) * 16;
  const int arow = (wy * 64 + fr) * 64 + sk;          // + mi*1024
  const int brow = 8192 + (wx * 64 + fr) * 64 + sk;   // + ni*1024

  #define STAGE(buf, kt)                                                        \
    {                                                                           \
      char* _d = lds + (buf) * 16384 + w * 2048;                                \
      const int _kn = (kt) * 64;                                                \
      _Pragma("unroll")                                                         \
      for (int q = 0; q < 2; ++q) {                                             \
        gload_lds16(gA + _kn + (size_t)(q * 16) * 512, _d + q * 1024);          \
        gload_lds16(gB + _kn + (size_t)(q * 16) * 512, _d + 8192 + q * 1024);   \
      }                                                                         \
    }

  STAGE(0, 0);   // prologue: tiles 0,1 in flight (8 loads/wave outstanding)
  STAGE(1, 1);

  #pragma unroll
  for (int t = 0; t < 8; ++t) {
    __builtin_amdgcn_s_barrier();            // raw: no vmcnt drain
    if (t < 6) STAGE((t + 2) % 3, t + 2);    // overwrites buf last read at t-1
    if (t < 6)       asm volatile("s_waitcnt vmcnt(8)" ::: "memory");  // S(t) landed
    else if (t == 6) asm volatile("s_waitcnt vmcnt(4)" ::: "memory");  // S(6) landed
    else             asm volatile("s_waitcnt vmcnt(0)" ::: "memory");  // tail

    const char* base = lds + (t % 3) * 16384;
    i32x4 aF[4], bF[4];
    #pragma unroll
    for (int mi = 0; mi < 4; ++mi) aF[mi] = *(const i32x4*)(base + arow + mi * 1024);
    #pragma unroll
    for (int ni = 0; ni < 4; ++ni) bF[ni] = *(const i32x4*)(base + brow + ni * 1024);
    #pragma unroll
    for (int mi = 0; mi < 4; ++mi)
      #pragma unroll
      for (int ni = 0; ni < 4; ++ni)
        acc[mi][ni] = __builtin_amdgcn_mfma_i32_16x16x64_i8(aF[mi], bF[ni], acc[mi][ni], 0, 0, 0);
  }
  #undef STAGE

  // ---- epilogue: exp, row-sums + col-sums; pos-pair direct write ----
  const float SC10 = 10.0f / 16129.0f;
  float rsum[4][4], csum[4];
  #pragma unroll
  for (int mi = 0; mi < 4; ++mi)
    #pragma unroll
    for (int r = 0; r < 4; ++r) rsum[mi][r] = 0.f;
  #pragma unroll
  for (int ni = 0; ni < 4; ++ni) csum[ni] = 0.f;

  #pragma unroll
  for (int mi = 0; mi < 4; ++mi) {
    #pragma unroll
    for (int ni = 0; ni < 4; ++ni) {
      const int lc = wx * 64 + ni * 16 + fr;
      #pragma unroll
      for (int r = 0; r < 4; ++r) {
        const int lr = wy * 64 + mi * 16 + g * 4 + r;
        const float l10 = (float)acc[mi][ni][r] * SC10;
        const float e = (isdiag && lc == lr) ? 0.f : __expf(l10 - 10.0f);
        rsum[mi][r] += e;
        csum[ni] += e;
        if (has_pos && lc == lr) {
          const float d = (float)acc[mi][ni][r] * (1.0f / 16129.0f);
          posArr[ib * BM + lr] = d;
          posArr[jb * BM + lr] = d;
        }
      }
    }
  }

  // row side: 16-lane DPP reduce (VALU); col side: 2 shuffles over g bits
  #pragma unroll
  for (int mi = 0; mi < 4; ++mi)
    #pragma unroll
    for (int r = 0; r < 4; ++r) rsum[mi][r] = sum16_dpp(rsum[mi][r]);
  #pragma unroll
  for (int ni = 0; ni < 4; ++ni) {
    float a = csum[ni];
    a += __shfl_xor(a, 16);
    a += __shfl_xor(a, 32);
    csum[ni] = a;
  }

  // cross-wave combine via LDS (aliases tile buffer; safe after barrier)
  __syncthreads();
  float* sc = (float*)lds;  // rS[wx][128]@0, cS[wy][128]@256 (floats)
  if (fr == 0) {
    #pragma unroll
    for (int mi = 0; mi < 4; ++mi)
      #pragma unroll
      for (int r = 0; r < 4; ++r) {
        const int row = wy * 64 + mi * 16 + g * 4 + r;
        sc[wx * 128 + row] = rsum[mi][r];
      }
  }
  if (g == 0) {
    #pragma unroll
    for (int ni = 0; ni < 4; ++ni) {
      const int col = wx * 64 + ni * 16 + fr;
      sc[256 + wy * 128 + col] = csum[ni];
    }
  }
  __syncthreads();

  if (tid < 128) {                     // rows of block ib -> slot jb
    const int row = tid;
    psum[(size_t)jb * NROW + ib * BM + row] = sc[row] + sc[128 + row];
  } else if (!isdiag) {                // rows of block jb -> slot ib (transpose side)
    const int col = tid - 128;
    psum[(size_t)ib * NROW + jb * BM + col] = sc[256 + col] + sc[384 + col];
  }
}

// ---------------- Kernel 3a: per-row loss, 256 partials (wide-parallel gather) ----------------
__global__ __launch_bounds__(128) void loss_stage1(const float* __restrict__ psum,
                                                   const float* __restrict__ posArr,
                                                   float* __restrict__ partial) {
  const int r5 = threadIdx.x & 31;       // row within block
  const int grp = threadIdx.x >> 5;      // slot group 0..3 (16 slots each)
  const int row = blockIdx.x * 32 + r5;
  float s = 0.f;
  #pragma unroll 4
  for (int sl = grp * 16; sl < grp * 16 + 16; ++sl)
    s += psum[(size_t)sl * NROW + row];
  __shared__ float red[4][32];
  red[grp][r5] = s;
  __syncthreads();
  if (threadIdx.x < 32) {
    const float tot = red[0][r5] + red[1][r5] + red[2][r5] + red[3][r5];
    float local = logf(tot) + 10.0f - 10.0f * posArr[row];
    #pragma unroll
    for (int m = 1; m < 32; m <<= 1) local += __shfl_xor(local, m);
    if (r5 == 0) partial[blockIdx.x] = local;
  }
}

// ---------------- Kernel 3b: final scalar (256 partials) ----------------
__global__ __launch_bounds__(256) void loss_stage2(const float* __restrict__ partial,
                                                   float* __restrict__ out) {
  float v = partial[threadIdx.x];
  #pragma unroll
  for (int m = 1; m < 64; m <<= 1) v += __shfl_xor(v, m);
  __shared__ float red[4];
  if ((threadIdx.x & 63) == 0) red[threadIdx.x >> 6] = v;
  __syncthreads();
  if (threadIdx.x == 0)
    out[0] = (red[0] + red[1] + red[2] + red[3]) * (1.0f / (float)BHALF);
}

extern "C" void kernel_launch(void* const* d_in, const int* in_sizes, int n_in,
                              void* d_out, int out_size, void* d_ws, size_t ws_size,
                              hipStream_t stream) {
  const float* feat = (const float*)d_in[0];
  char* ws = (char*)d_ws;
  signed char* f8 = (signed char*)ws;                              // 4 MB
  float* psum = (float*)(ws + (size_t)NROW * 512);                 // NB*NROW floats (2 MB)
  float* posArr = psum + (size_t)NB * NROW;                        // 32 KB
  float* partial = posArr + NROW;                                  // 1 KB
  float* out = (float*)d_out;

  normalize_kernel<<<NROW / 4, 256, 0, stream>>>(feat, f8);
  pair_gram_kernel<<<NPAIR, 256, 0, stream>>>(f8, psum, posArr);
  loss_stage1<<<NROW / 32, 128, 0, stream>>>(psum, posArr, partial);
  loss_stage2<<<1, 256, 0, stream>>>(partial, out);
}